// Round 1
// baseline (2245.573 us; speedup 1.0000x reference)
//
#include <hip/hip_runtime.h>
#include <hip/hip_bf16.h>

#define NH 4
#define DH 256
#define DMODEL 1024
#define BB 4
#define SS 2048

typedef __attribute__((ext_vector_type(4))) float f32x4;
typedef __attribute__((ext_vector_type(8))) short bf16x8;
typedef __attribute__((ext_vector_type(4))) int i32x4;

__device__ __forceinline__ int dot4i8(int acc, int a, int b) {
#if __has_builtin(__builtin_amdgcn_sdot4)
    return __builtin_amdgcn_sdot4(a, b, acc, false);
#else
#pragma unroll
    for (int i = 0; i < 4; ++i) {
        int av = (a << (24 - 8 * i)) >> 24;
        int bv = (b << (24 - 8 * i)) >> 24;
        acc += av * bv;
    }
    return acc;
#endif
}

// Raw workgroup barrier: LDS-ordering only. Does NOT drain vmcnt, so global
// loads (gate prefetch) and stores (y) stay in flight across the barrier.
__device__ __forceinline__ void wg_barrier() {
    __builtin_amdgcn_sched_barrier(0);
    asm volatile("s_waitcnt lgkmcnt(0)" ::: "memory");
    __builtin_amdgcn_s_barrier();
    __builtin_amdgcn_sched_barrier(0);
}

// ---------------- conv + swish ----------------
__global__ void k_conv(const float* __restrict__ x, const float* __restrict__ cw,
                       const float* __restrict__ cb, float* __restrict__ xc) {
    int bs = blockIdx.x;              // b*2048 + s
    int s = bs & (SS - 1);
    const float* xrow = x + (size_t)bs * DMODEL;
#pragma unroll
    for (int dd = 0; dd < 4; ++dd) {
        int d = threadIdx.x + dd * 256;
        float w0 = cw[d * 4 + 0], w1 = cw[d * 4 + 1], w2 = cw[d * 4 + 2], w3 = cw[d * 4 + 3];
        float acc = cb[d] + w3 * xrow[d];
        if (s >= 1) acc += w2 * xrow[d - DMODEL];
        if (s >= 2) acc += w1 * xrow[d - 2 * DMODEL];
        if (s >= 3) acc += w0 * xrow[d - 3 * DMODEL];
        float sig = 1.f / (1.f + __expf(-acc));
        xc[(size_t)bs * DMODEL + d] = acc * sig;
    }
}

// ---------------- headwise projections (bf16 MFMA GEMM) ----------------
// grid: (M/64=128, 512/64=8, 8 instances). instance z = h*2 + pair.
// pair0: {i,f} from x_conv ; pair1: {z,o} from x.
// gates layout: [b][h][s][d][g]  (g innermost -> one float4 per (s,d) in k_scan)
__global__ void k_gemm(const float* __restrict__ x, const float* __restrict__ xc,
                       const float* __restrict__ wi, const float* __restrict__ wf,
                       const float* __restrict__ wz, const float* __restrict__ wo,
                       float* __restrict__ gates) {
    int h = blockIdx.z >> 1, pair = blockIdx.z & 1;
    const float* A = pair ? x : xc;
    int n0 = blockIdx.y * 64;  // in [0,512)
    const float* W = (n0 < 256) ? (pair ? wz : wi) : (pair ? wo : wf);
    int nl = n0 & 255;
    int m0 = blockIdx.x * 64;

    __shared__ __align__(16) __hip_bfloat16 Al[64][72];
    __shared__ __align__(16) __hip_bfloat16 Bl[64][72];

    int tid = threadIdx.x;
    int lane = tid & 63, wv = tid >> 6;
    f32x4 acc[4] = {};

    for (int k0 = 0; k0 < 256; k0 += 64) {
        __syncthreads();
#pragma unroll
        for (int i = 0; i < 4; ++i) {
            int f4 = tid + i * 256;
            int r = f4 >> 4, c4 = (f4 & 15) * 4;
            const float* srcA = A + (size_t)(m0 + r) * DMODEL + h * DH + k0 + c4;
            float4 v = *(const float4*)srcA;
            Al[r][c4 + 0] = __float2bfloat16(v.x);
            Al[r][c4 + 1] = __float2bfloat16(v.y);
            Al[r][c4 + 2] = __float2bfloat16(v.z);
            Al[r][c4 + 3] = __float2bfloat16(v.w);
            const float* srcB = W + (size_t)(h * DH + nl + r) * DH + k0 + c4;
            float4 u = *(const float4*)srcB;
            Bl[r][c4 + 0] = __float2bfloat16(u.x);
            Bl[r][c4 + 1] = __float2bfloat16(u.y);
            Bl[r][c4 + 2] = __float2bfloat16(u.z);
            Bl[r][c4 + 3] = __float2bfloat16(u.w);
        }
        __syncthreads();
#pragma unroll
        for (int kk = 0; kk < 64; kk += 32) {
            bf16x8 a = *(const bf16x8*)&Al[wv * 16 + (lane & 15)][kk + (lane >> 4) * 8];
#pragma unroll
            for (int nt = 0; nt < 4; ++nt) {
                bf16x8 bfr = *(const bf16x8*)&Bl[nt * 16 + (lane & 15)][kk + (lane >> 4) * 8];
                acc[nt] = __builtin_amdgcn_mfma_f32_16x16x32_bf16(a, bfr, acc[nt], 0, 0, 0);
            }
        }
    }
    // epilogue: gates[b][h][s][d][g]  (g innermost)
#pragma unroll
    for (int nt = 0; nt < 4; ++nt)
#pragma unroll
        for (int r = 0; r < 4; ++r) {
            int m = m0 + wv * 16 + (lane >> 4) * 4 + r;
            int n = n0 + nt * 16 + (lane & 15);
            int b = m >> 11, s = m & (SS - 1);
            int g = pair * 2 + (n >> 8), d = n & 255;
            gates[((((size_t)(b * NH + h)) * SS + s) * DH + d) * 4 + g] = acc[nt][r];
        }
}

// ---------------- weight prep: per-column int8 quantization of R ----------------
// one wave per column k of head h. lane covers d = 4*lane .. 4*lane+3.
__global__ void k_prep(const float* __restrict__ R, int* __restrict__ Wq,
                       float* __restrict__ scales) {
    int colid = blockIdx.x * 4 + (threadIdx.x >> 6);  // 0..4095
    int lane = threadIdx.x & 63;
    int h = colid >> 10, k = colid & 1023;
    const float* base = R + (size_t)h * 256 * 1024 + k;
    float v[4];
    float mx = 0.f;
#pragma unroll
    for (int i = 0; i < 4; ++i) {
        v[i] = base[(size_t)(lane * 4 + i) * 1024];
        mx = fmaxf(mx, fabsf(v[i]));
    }
    for (int off = 32; off; off >>= 1) mx = fmaxf(mx, __shfl_xor(mx, off));
    mx = fmaxf(mx, 1e-30f);
    float scale = mx * (1.f / 127.f);
    float inv = 127.f / mx;
    int pk = 0;
#pragma unroll
    for (int i = 0; i < 4; ++i) {
        int q = (int)rintf(v[i] * inv);
        q = max(-127, min(127, q));
        pk |= (q & 255) << (8 * i);
    }
    Wq[(h * 64 + lane) * 1024 + k] = pk;
    if (lane == 0) scales[h * 1024 + k] = scale;
}

// ---------------- the sequential sLSTM scan ----------------
// 16 blocks, one per (b,h). 1024 threads; thread t owns rec column t.
// Weights int8 register-resident (64 dwords/thread). h quantized to i8 (|h|<1).
// Latency fixes vs previous version:
//   * raw barriers (lgkmcnt only) -> gate loads / y store-acks not drained per step
//   * distance-1 register prefetch of next step's gates (single float4 load)
//   * 4 independent dot accumulators (chain depth 64 -> 16)
__launch_bounds__(1024, 4)
__global__ void k_scan(const float* __restrict__ gates, const int* __restrict__ Wq,
                       const float* __restrict__ scales, const float* __restrict__ bias,
                       float* __restrict__ y) {
    int bh = blockIdx.x;
    int h = bh & 3;
    int t = threadIdx.x;

    __shared__ __align__(16) signed char hq[256];
    __shared__ float rec[1024];

    int w[64];
#pragma unroll
    for (int j = 0; j < 64; ++j) w[j] = Wq[(h * 64 + j) * 1024 + t];
    float colmul = scales[h * 1024 + t] * (1.f / 127.f);

    float c = 0.f, n = 0.f, mstate = 0.f;
    float bi = 0.f, bf_ = 0.f, bz = 0.f, bo = 0.f;
    int d = t & 255;
    if (t < 256) {
        bi = bias[(0 * NH + h) * DH + d];
        bf_ = bias[(1 * NH + h) * DH + d];
        bz = bias[(2 * NH + h) * DH + d];
        bo = bias[(3 * NH + h) * DH + d];
    }
    if (t < 16) ((i32x4*)hq)[t] = (i32x4){0, 0, 0, 0};
    const float4* gp = (const float4*)(gates + (size_t)bh * SS * 1024) + d;  // [s][d][g], step stride = 256 float4
    float* ybase = y + (size_t)bh * SS * DH;
    __syncthreads();

    float4 gc = {0.f, 0.f, 0.f, 0.f};
    if (t < 256) gc = gp[0];

    for (int s = 0; s < SS; ++s) {
        // prefetch next step's gates; rides in flight under dots + both barriers
        float4 gn = gc;
        if (t < 256 && s + 1 < SS) gn = gp[(size_t)(s + 1) * 256];

        // rec = (i8 h) . (i8 W column t), 4 independent chains
        int accs[4];
#pragma unroll
        for (int g4 = 0; g4 < 4; ++g4) {
            i32x4 h0 = ((const i32x4*)hq)[g4 * 4 + 0];
            i32x4 h1 = ((const i32x4*)hq)[g4 * 4 + 1];
            i32x4 h2 = ((const i32x4*)hq)[g4 * 4 + 2];
            i32x4 h3 = ((const i32x4*)hq)[g4 * 4 + 3];
            int a = 0;
            a = dot4i8(a, w[g4 * 16 + 0], h0.x);
            a = dot4i8(a, w[g4 * 16 + 1], h0.y);
            a = dot4i8(a, w[g4 * 16 + 2], h0.z);
            a = dot4i8(a, w[g4 * 16 + 3], h0.w);
            a = dot4i8(a, w[g4 * 16 + 4], h1.x);
            a = dot4i8(a, w[g4 * 16 + 5], h1.y);
            a = dot4i8(a, w[g4 * 16 + 6], h1.z);
            a = dot4i8(a, w[g4 * 16 + 7], h1.w);
            a = dot4i8(a, w[g4 * 16 + 8], h2.x);
            a = dot4i8(a, w[g4 * 16 + 9], h2.y);
            a = dot4i8(a, w[g4 * 16 + 10], h2.z);
            a = dot4i8(a, w[g4 * 16 + 11], h2.w);
            a = dot4i8(a, w[g4 * 16 + 12], h3.x);
            a = dot4i8(a, w[g4 * 16 + 13], h3.y);
            a = dot4i8(a, w[g4 * 16 + 14], h3.z);
            a = dot4i8(a, w[g4 * 16 + 15], h3.w);
            accs[g4] = a;
        }
        rec[t] = (float)(accs[0] + accs[1] + accs[2] + accs[3]) * colmul;
        wg_barrier();
        if (t < 256) {
            float ri = rec[d], rf = rec[256 + d], rz = rec[512 + d], ro = rec[768 + d];
            float rawi = gc.x + ri + bi;
            float rawf = gc.y + rf + bf_;
            float rawz = gc.z + rz + bz;
            float rawo = gc.w + ro + bo;
            // log_sigmoid(rawf) = min(rawf,0) - log1p(exp(-|rawf|))
            float lsf = fminf(rawf, 0.f) - __logf(1.f + __expf(-fabsf(rawf)));
            float lfm = mstate + lsf;
            float mn = fmaxf(rawi, lfm);
            float ig = __expf(rawi - mn);
            float fg = __expf(lfm - mn);
            float az = fabsf(rawz);
            float e2 = __expf(-2.f * az);
            float th = (1.f - e2) / (1.f + e2);
            th = rawz < 0.f ? -th : th;
            c = fg * c + ig * th;
            n = fg * n + ig;
            mstate = mn;
            float so = 1.f / (1.f + __expf(-rawo));
            float hv = so * c / n;
            ybase[(size_t)s * DH + d] = hv;
            int q = (int)rintf(hv * 127.f);
            hq[d] = (signed char)q;
        }
        gc = gn;
        wg_barrier();
    }
}

// ---------------- multihead layernorm + transpose ----------------
__global__ void k_ln(const float* __restrict__ y, const float* __restrict__ gsc,
                     const float* __restrict__ gbi, float* __restrict__ out) {
    int bid = blockIdx.x;  // bh*2048 + s
    int s = bid & (SS - 1);
    int bh = bid >> 11;
    int b = bh >> 2, h = bh & 3;
    int d = threadIdx.x;
    float v = y[(size_t)bid * DH + d];
    float s1 = v, s2 = v * v;
    for (int off = 32; off; off >>= 1) {
        s1 += __shfl_xor(s1, off);
        s2 += __shfl_xor(s2, off);
    }
    __shared__ float a1[4], a2[4];
    int wv = threadIdx.x >> 6, ln = threadIdx.x & 63;
    if (ln == 0) { a1[wv] = s1; a2[wv] = s2; }
    __syncthreads();
    s1 = a1[0] + a1[1] + a1[2] + a1[3];
    s2 = a2[0] + a2[1] + a2[2] + a2[3];
    float mu = s1 * (1.f / 256.f);
    float var = s2 * (1.f / 256.f) - mu * mu;
    float rs = rsqrtf(var + 1e-6f);
    float o = (v - mu) * rs * gsc[h * DH + d] + gbi[h * DH + d];
    out[((size_t)(b * SS + s)) * DMODEL + h * DH + d] = o;
}

extern "C" void kernel_launch(void* const* d_in, const int* in_sizes, int n_in,
                              void* d_out, int out_size, void* d_ws, size_t ws_size,
                              hipStream_t stream) {
    (void)in_sizes; (void)n_in; (void)out_size; (void)ws_size;
    const float* x = (const float*)d_in[0];
    const float* cw = (const float*)d_in[1];
    const float* cb = (const float*)d_in[2];
    const float* wi = (const float*)d_in[3];
    const float* wf = (const float*)d_in[4];
    const float* wz = (const float*)d_in[5];
    const float* wo = (const float*)d_in[6];
    const float* R = (const float*)d_in[7];
    const float* cbias = (const float*)d_in[8];
    const float* gsc = (const float*)d_in[9];
    const float* gbi = (const float*)d_in[10];
    float* out = (float*)d_out;

    char* ws = (char*)d_ws;
    float* xc = (float*)ws;                           // 33,554,432 B
    float* gates = (float*)(ws + 33554432ull);        // 134,217,728 B
    float* yb = (float*)(ws + 167772160ull);          // 33,554,432 B
    int* Wq = (int*)(ws + 201326592ull);              // 1,048,576 B
    float* scales = (float*)(ws + 202375168ull);      // 16,384 B

    k_prep<<<1024, 256, 0, stream>>>(R, Wq, scales);
    k_conv<<<BB * SS, 256, 0, stream>>>(x, cw, cb, xc);
    k_gemm<<<dim3(128, 8, 8), 256, 0, stream>>>(x, xc, wi, wf, wz, wo, gates);
    k_scan<<<16, 1024, 0, stream>>>(gates, Wq, scales, cbias, yb);
    k_ln<<<BB * SS * NH, 256, 0, stream>>>(yb, gsc, gbi, out);
}